// Round 8
// baseline (1028.465 us; speedup 1.0000x reference)
//
#include <hip/hip_runtime.h>
#include <math.h>

// ---------------- problem constants ----------------
#define B_ 8192
#define T_ 223
#define D_ 7
#define H_ 128
#define E_ 50
#define O_ 29
#define A_ 9
#define TD_ (T_*D_)     // 1561
#define NB 16           // batch rows per block -> grid 512 = 2 blocks/CU @128 VGPR
#define NTHR 512
#define MB 8            // batch rows per block (head kernel)
#define MS_BG 128       // msum batch groups

// ---------------- workspace layout (float offsets) ----------------
#define WS_MINV  0                            // raw msum_t sums, T floats
#define WS_ACC   (WS_MINV + T_)               // [0]=x_loss raw sum, [1]=y_loss raw sum
#define WS_WCATT (WS_ACC + 2)                 // [178][128] transposed W_cat
#define WS_HFIN  (WS_WCATT + 178*H_)          // final h, [B][128] fp32

// ---------------- output layout (floats) ----------------
#define OUT_YH  3
#define OUT_IMP (OUT_YH + B_*O_)              // 237571
#define OUT_LAB (OUT_IMP + B_*T_*D_)          // 13025283

typedef __attribute__((ext_vector_type(8))) short short8;   // 8 bf16 = 4 VGPRs
typedef __attribute__((ext_vector_type(4))) float floatx4;
#define MFMA16(Av,Bv,Cv) __builtin_amdgcn_mfma_f32_16x16x32_bf16((Av),(Bv),(Cv),0,0,0)

// raw barrier: drain LDS only (producer/consumer ordering); do NOT drain
// vmcnt -- global prefetch loads ride across and land during the next phase.
#define BARRIER() do { asm volatile("s_waitcnt lgkmcnt(0)" ::: "memory"); \
                       __builtin_amdgcn_s_barrier(); } while (0)

__device__ __forceinline__ unsigned short f2bf(float f) {   // RNE fp32->bf16
    unsigned int u = __builtin_bit_cast(unsigned int, f);
    return (unsigned short)((u + 0x7FFFu + ((u >> 16) & 1u)) >> 16);
}
__device__ __forceinline__ float bf2f(unsigned short s) {
    unsigned int u = ((unsigned int)s) << 16;
    return __builtin_bit_cast(float, u);
}
__device__ __forceinline__ float rcp_(float x)  { return __builtin_amdgcn_rcpf(x); }
__device__ __forceinline__ float sigm(float x)  { return rcp_(1.f + __expf(-x)); }
__device__ __forceinline__ float tanh_(float x) { return 1.f - 2.f*rcp_(1.f + __expf(2.f*x)); }

// ================= prep: W_cat transpose + zero accumulators =================
__global__ void rits_prep(const float* __restrict__ W_cat, float* __restrict__ ws)
{
    int idx = blockIdx.x * 256 + threadIdx.x;
    if (idx < H_*178) {                      // W_cat [128][178] -> [178][128]
        int j = idx / 178, k = idx - j*178;
        ws[WS_WCATT + k*H_ + j] = W_cat[idx];
    }
    if (idx < T_) ws[WS_MINV + idx] = 0.f;
    if (idx < 2) ws[WS_ACC + idx] = 0.f;
}

// ================= per-step mask sums (coalesced, atomic partials) =================
__global__ void rits_msum(const float* __restrict__ masks, float* __restrict__ ws)
{
    const int tc = blockIdx.x % 7;           // t-chunk of 32 steps
    const int bg = blockIdx.x / 7;           // batch group
    const int t0 = tc * 32;
    const int nt = (t0 + 32 <= T_) ? 32 : (T_ - t0);
    const int ncol = nt * D_;                // 224 or 217
    const int tid = threadIdx.x;
    __shared__ float sums[224];
    float s = 0.f;
    if (tid < ncol) {
        const int bpg = B_ / MS_BG;          // 64
        const float* p = masks + (size_t)bg * bpg * TD_ + (size_t)t0 * D_ + tid;
        #pragma unroll 4
        for (int b = 0; b < bpg; ++b) s += p[(size_t)b * TD_];
    }
    if (tid < 224) sums[tid] = (tid < ncol) ? s : 0.f;
    __syncthreads();
    if (tid < 32) {
        float r = 0.f;
        #pragma unroll
        for (int q = 0; q < 7; ++q) r += sums[tid*7 + q];
        if (t0 + tid < T_) atomicAdd(&ws[WS_MINV + t0 + tid], r);
    }
}

// ================= main scan kernel (MFMA) =================
// R7 structure (717us main) with ONE isolated change: NB 32->16, grid 512,
// launch_bounds STAYS (512,2).  Per-wave regs drop ~24 (acc[4][2]->acc[4],
// single B-tile) so allocation stays <=128 unified regs -> hardware fits
// 4 waves/SIMD -> TWO co-resident 8-wave blocks per CU.  Per-CU issue work
// per step is unchanged; the async second block fills barrier/serial-phase
// stalls (VALUBusy 55% -> target 70-80%).
// Also fixes the R7 msum off-by-one: invt now uses msums[t] (saved before
// rmv is overwritten with msums[t+1]).
__global__ __launch_bounds__(NTHR, 2) void rits_main(
    const float* __restrict__ values, const float* __restrict__ masks, const float* __restrict__ deltas,
    const float* __restrict__ W_td_h, const float* __restrict__ b_td_h,
    const float* __restrict__ W_td_x, const float* __restrict__ b_td_x,
    const float* __restrict__ W_hist, const float* __restrict__ b_hist,
    const float* __restrict__ W_feat, const float* __restrict__ b_feat,
    const float* __restrict__ W_comb, const float* __restrict__ b_comb,
    const float* __restrict__ W_ih, const float* __restrict__ W_hh,
    const float* __restrict__ b_ih, const float* __restrict__ b_hh,
    float* __restrict__ ws, float* __restrict__ out)
{
    // hbuf row (bf16, stride 168): 0..127 h, 128..134 c_c, 135..159 zeros
    __shared__ __attribute__((aligned(16))) unsigned short hbuf[NB*168];
    // bbuf row (bf16, stride 32): 0..6 m(t), 7=1.0, 8..14 d(t+1), 15=1.0, 16..31=0
    __shared__ __attribute__((aligned(16))) unsigned short bbuf[NB*32];
    __shared__ __attribute__((aligned(16))) unsigned short whis_lds[16*136]; // W_hist bf16, rows 7..15 = 0
    __shared__ float xm_l[NB*18];           // (x,m) float2 pairs, stride 18 (conflict-free)
    __shared__ float gx_l[NB*9];            // gamma_x, stride 9
    __shared__ float xh_l[NB*10];           // x_h raw (bias added), stride 10, float2-aligned
    __shared__ float impbuf[NB*16*7];       // 16-step imputation buffer (fp32)
    __shared__ float red[8];

    const int tid  = threadIdx.x;
    const int b0   = blockIdx.x * NB;
    const int lane = tid & 63;
    const int w    = tid >> 6;      // wave 0..7
    const int quad = lane >> 4;
    const int l15  = lane & 15;

    // ---- one-time LDS init ----
    for (int i = tid; i < NB*168; i += NTHR) hbuf[i] = 0;
    for (int i = tid; i < NB*32;  i += NTHR) bbuf[i] = 0;
    for (int i = tid; i < 16*136; i += NTHR) {
        int r = i / 136, c = i - r*136;
        whis_lds[i] = (r < 7 && c < 128) ? f2bf(W_hist[r*H_ + c]) : 0;
    }
    __syncthreads();                 // zeros visible before bias-column pokes
    if (tid < NB) {
        bbuf[tid*32 + 7]  = 0x3F80;  // 1.0 -> gate-bias column
        bbuf[tid*32 + 15] = 0x3F80;  // 1.0 -> decay-bias column
    }

    // ---- persistent weight fragments (per lane) ----
    short8 whhf[4][4];   // [gate c][kstep]  A[j=l15 of tile][k=quad*8+e]
    short8 winf_c[4];    // c_c part: k0..6 = W_ih[:, 0..6], rest 0
    short8 winf_mb[4];   // m part:   k0..6 = W_ih[:, 7..13], k7 = b_ih+b_hh, rest 0
    short8 wtdf;         // decay:    k8..14 = W_td_h, k15 = b_td_h, rest 0
    float  bh_r[4];      // b_hist for wave7 publish
    {
        union UU { short8 v; unsigned short u[8]; } fr;
        #pragma unroll
        for (int c = 0; c < 4; ++c) {
            const int j = (c*8 + w)*16 + l15;
            #pragma unroll
            for (int s = 0; s < 4; ++s) {
                const float* p = W_hh + j*H_ + s*32 + quad*8;
                #pragma unroll
                for (int e = 0; e < 8; ++e) fr.u[e] = f2bf(p[e]);
                whhf[c][s] = fr.v;
            }
            #pragma unroll
            for (int e = 0; e < 8; ++e) {
                int k = quad*8 + e;
                fr.u[e] = (k < 7) ? f2bf(W_ih[j*14 + k]) : (unsigned short)0;
            }
            winf_c[c] = fr.v;
            #pragma unroll
            for (int e = 0; e < 8; ++e) {
                int k = quad*8 + e;
                float v = (k < 7) ? W_ih[j*14 + 7 + k]
                        : ((k == 7) ? (b_ih[j] + b_hh[j]) : 0.f);
                fr.u[e] = f2bf(v);
            }
            winf_mb[c] = fr.v;
        }
        const int j2 = w*16 + l15;
        #pragma unroll
        for (int e = 0; e < 8; ++e) {
            int k = quad*8 + e;
            float v = (k >= 8 && k < 15) ? W_td_h[j2*D_ + (k - 8)]
                    : ((k == 15) ? b_td_h[j2] : 0.f);
            fr.u[e] = f2bf(v);
        }
        wtdf = fr.v;
        #pragma unroll
        for (int r = 0; r < 4; ++r) {
            int f = quad*4 + r;
            bh_r[r] = (quad < 2 && f < 7) ? b_hist[f] : 0.f;
        }
    }

    // ---- A3 per-thread state (tid < 112: 16 rows x 7 features) ----
    const bool ldr = (tid < NB*D_);
    const int  lb  = tid / D_, li = tid - (tid/D_)*D_;
    float wfr[7], wcr[14], bfr = 0.f, bcr = 0.f, tdx_own = 0.f, btdx_own = 0.f;
    if (ldr) {
        #pragma unroll
        for (int k = 0; k < 7; ++k)  wfr[k] = (k == li) ? 0.f : W_feat[li*D_ + k];
        #pragma unroll
        for (int k = 0; k < 14; ++k) wcr[k] = W_comb[li*14 + k];
        bfr = b_feat[li];  bcr = b_comb[li];
        tdx_own = W_td_x[li*D_ + li];  btdx_own = b_td_x[li];
    }

    float c_st[4] = {0,0,0,0};
    float lacc = 0.f;

    // input prefetch (regs hold step-t data at loop top)
    const long gbase = (long)(b0 + lb)*TD_ + li;
    float rx = 0.f, rm = 0.f, rd = 0.f;
    const float* msums = ws + WS_MINV;
    float rmv = 0.f;
    if (ldr) { rx = values[gbase]; rm = masks[gbase]; rd = deltas[gbase]; rmv = msums[0]; }

    for (int t = 0; t < T_; ++t) {
        // ---- stage step-t data (consumes rx/rm/rd), then ISSUE t+1 loads ----
        float msum_cur = rmv;                  // msums[t] (saved BEFORE overwrite)
        if (ldr) {
            float2 s2 = { rx, rm };
            *(float2*)&xm_l[lb*18 + 2*li] = s2;
            gx_l[lb*9 + li] = __expf(-fmaxf(fmaf(rd, tdx_own, btdx_own), 0.f));
            bbuf[lb*32 + li] = f2bf(rm);
            if (t + 1 < T_) {
                const long g = gbase + (long)(t+1)*D_;
                rx = values[g]; rm = masks[g]; rd = deltas[g];   // ride across [S]
                rmv = msums[t+1];                                 // for NEXT step
            }
        }
        BARRIER();                             // [S] stage + prev h-writes visible (LDS only)

        // ---- I1: gate h-part (+ x_h on wave 7). h in hbuf is ALREADY decayed ----
        floatx4 acc[4];
        #pragma unroll
        for (int c = 0; c < 4; ++c) { floatx4 z = {0,0,0,0}; acc[c] = z; }
        floatx4 xh0 = {0,0,0,0};
        #pragma unroll
        for (int s = 0; s < 4; ++s) {
            short8 hb0 = *(const short8*)&hbuf[l15*168 + s*32 + quad*8];
            #pragma unroll
            for (int c = 0; c < 4; ++c)
                acc[c] = MFMA16(whhf[c][s], hb0, acc[c]);
            if (w == 7) {
                short8 wh = *(const short8*)&whis_lds[l15*136 + s*32 + quad*8];
                xh0 = MFMA16(wh, hb0, xh0);
            }
        }
        // wave 7: publish raw x_h (bias added) as float2 pairs — short tail
        if (w == 7 && quad < 2) {
            const int b = l15;
            float2 p0 = { xh0[0] + bh_r[0], xh0[1] + bh_r[1] };
            float2 p1 = { xh0[2] + bh_r[2], xh0[3] + bh_r[3] };
            *(float2*)&xh_l[b*10 + quad*4]     = p0;
            *(float2*)&xh_l[b*10 + quad*4 + 2] = p1;
        }
        BARRIER();                             // [B] x_h ready

        // ---- I2: m-part + gate-bias MFMAs (all waves) ----
        {
            short8 bb0 = *(const short8*)&bbuf[l15*32 + quad*8];
            #pragma unroll
            for (int c = 0; c < 4; ++c)
                acc[c] = MFMA16(winf_mb[c], bb0, acc[c]);
        }

        // ---- A3: z_h, alpha, c_h, c_c, imputation, loss; + bbuf-d write ----
        if (ldr) {
            const int b = lb, i = li;
            const float invt = rcp_(msum_cur + 1e-5f);
            const float x = xm_l[b*18 + 2*i], m = xm_l[b*18 + 2*i + 1];
            const float xhv = xh_l[b*10 + i];
            float zh = bfr, al = bcr;
            #pragma unroll
            for (int k = 0; k < 7; ++k) {
                const float xk  = xm_l[b*18 + 2*k];
                const float mk  = xm_l[b*18 + 2*k + 1];
                const float xhk = xh_l[b*10 + k];
                const float xck = mk*xk + (1.f - mk)*xhk;
                zh = fmaf(wfr[k], xck, zh);
                al = fmaf(wcr[k], gx_l[b*9 + k], al);
                al = fmaf(wcr[7+k], mk, al);
            }
            const float ch = al*zh + (1.f - al)*xhv;
            const float cc = m*x + (1.f - m)*ch;
            impbuf[(b*16 + (t & 15))*7 + i] = cc;
            hbuf[b*168 + 128 + i] = f2bf(cc);
            lacc = fmaf((fabsf(x-xhv) + fabsf(x-zh) + fabsf(x-ch)) * m, invt, lacc);
            if (t + 1 < T_)
                bbuf[lb*32 + 8 + li] = f2bf(rd);   // d(t+1), prefetched at loop-top
        }
        BARRIER();                             // [C] c_c ext + bbuf-d ready

        // ---- I3: c_c-part MFMA + decay MFMA ----
        {
            short8 ib0 = *(const short8*)&hbuf[l15*168 + 128 + quad*8];
            #pragma unroll
            for (int c = 0; c < 4; ++c)
                acc[c] = MFMA16(winf_c[c], ib0, acc[c]);
        }
        const bool dec = (t + 1 < T_);
        floatx4 g0 = {0,0,0,0};
        if (dec) {
            short8 bb0 = *(const short8*)&bbuf[l15*32 + quad*8];
            floatx4 z = {0,0,0,0};
            g0 = MFMA16(wtdf, bb0, z);
        }
        // ---- LSTM update; write h (pre-decayed for next step) as b64 ----
        {
            const int b = l15;
            float hnv[4];
            #pragma unroll
            for (int r = 0; r < 4; ++r) {
                float ig = acc[0][r], fg = acc[1][r];
                float gv = acc[2][r], og = acc[3][r];
                float cn = sigm(fg)*c_st[r] + sigm(ig)*tanh_(gv);
                c_st[r] = cn;
                float hn = sigm(og)*tanh_(cn);
                if (dec) hn *= __expf(-fmaxf(g0[r], 0.f));
                hnv[r] = hn;
            }
            uint2 pk;
            pk.x = (unsigned)f2bf(hnv[0]) | ((unsigned)f2bf(hnv[1]) << 16);
            pk.y = (unsigned)f2bf(hnv[2]) | ((unsigned)f2bf(hnv[3]) << 16);
            *(uint2*)&hbuf[b*168 + w*16 + quad*4] = pk;
        }

        // ---- imputation flush (contiguous 28B runs, 16 steps at a time) ----
        if ((t & 15) == 15 || t == T_ - 1) {
            const int t0 = t & ~15;
            const int b  = tid >> 4, c16 = tid & 15;
            if (b < NB && t0 + c16 <= t) {
                float* gp = out + (size_t)OUT_IMP + (size_t)(b0+b)*TD_ + (size_t)(t0+c16)*D_;
                const float* lp = &impbuf[(b*16 + c16)*7];
                #pragma unroll
                for (int e = 0; e < 7; ++e) gp[e] = lp[e];
            }
        }
    }
    __syncthreads();

    // ---- x_loss partial reduction ----
    for (int off = 32; off > 0; off >>= 1) lacc += __shfl_down(lacc, off, 64);
    if ((tid & 63) == 0) red[tid >> 6] = lacc;
    __syncthreads();
    if (tid == 0) {
        float s = 0.f;
        #pragma unroll
        for (int q = 0; q < 8; ++q) s += red[q];
        atomicAdd(&ws[WS_ACC], s);
    }
    // ---- final h -> workspace (fp32) ----
    for (int i = tid; i < NB*H_; i += NTHR) {
        int b = i >> 7, j = i & 127;
        ws[WS_HFIN + (size_t)(b0+b)*H_ + j] = bf2f(hbuf[b*168 + j]);
    }
}

// ================= classification head =================
__global__ __launch_bounds__(128) void rits_head(
    const float* __restrict__ probs, const float* __restrict__ ancillary, const int* __restrict__ labels,
    const float* __restrict__ W_anc, const float* __restrict__ b_anc,
    const float* __restrict__ b_cat,
    const float* __restrict__ W_out, const float* __restrict__ b_out,
    float* __restrict__ ws, float* __restrict__ out)
{
    __shared__ float hb[MB*H_];
    __shared__ float ancl[MB*52];
    __shared__ float hc[MB*H_];
    __shared__ float lg[MB*32];
    __shared__ float smx[MB], sinv[MB], ysum[MB];
    __shared__ float sq[MB*32];
    const int tid = threadIdx.x;
    const int bb0 = blockIdx.x * MB;

    for (int i = tid; i < MB*H_; i += 128) hb[i] = ws[WS_HFIN + (size_t)bb0*H_ + i];
    for (int i = tid; i < MB*E_; i += 128) {
        int b = i / E_, e = i - b*E_;
        float s = b_anc[e];
        #pragma unroll
        for (int a = 0; a < A_; ++a) s = fmaf(ancillary[(bb0+b)*A_ + a], W_anc[e*A_ + a], s);
        ancl[b*52+e] = fmaxf(s, 0.f);
    }
    __syncthreads();
    {
        const int j = tid;
        float s[MB];
        #pragma unroll
        for (int b = 0; b < MB; ++b) s[b] = b_cat[j];
        const float* wc = ws + WS_WCATT;
        for (int k = 0; k < H_; ++k) {
            float wv = wc[k*H_ + j];
            #pragma unroll
            for (int b = 0; b < MB; ++b) s[b] = fmaf(hb[b*H_+k], wv, s[b]);
        }
        for (int k = 0; k < E_; ++k) {
            float wv = wc[(H_+k)*H_ + j];
            #pragma unroll
            for (int b = 0; b < MB; ++b) s[b] = fmaf(ancl[b*52+k], wv, s[b]);
        }
        #pragma unroll
        for (int b = 0; b < MB; ++b) hc[b*H_+j] = fmaxf(s[b], 0.f);
    }
    __syncthreads();
    for (int i = tid; i < MB*O_; i += 128) {
        int b = i / O_, o = i - b*O_;
        float s = b_out[o];
        for (int k = 0; k < H_; ++k) s = fmaf(hc[b*H_+k], W_out[o*H_+k], s);
        lg[b*32+o] = s;
    }
    __syncthreads();
    if (tid < MB) {
        float mx = -1e30f;
        for (int o = 0; o < O_; ++o) mx = fmaxf(mx, lg[tid*32+o]);
        float se = 0.f;
        for (int o = 0; o < O_; ++o) se += __expf(lg[tid*32+o] - mx);
        smx[tid] = mx; sinv[tid] = 1.f / se;
    }
    __syncthreads();
    for (int i = tid; i < MB*O_; i += 128) {
        int b = i / O_, o = i - b*O_;
        float y = __expf(lg[b*32+o] - smx[b]) * sinv[b];
        out[OUT_YH + (size_t)(bb0+b)*O_ + o] = y;
        float d = y - probs[(size_t)(bb0+b)*O_ + o];
        sq[b*32+o] = d*d;
    }
    __syncthreads();
    if (tid < MB) {
        float s = 0.f;
        for (int o = 0; o < O_; ++o) s += sq[tid*32+o];
        ysum[tid] = s;
        out[OUT_LAB + bb0 + tid] = (float)labels[bb0 + tid];
    }
    __syncthreads();
    if (tid == 0) {
        float s = 0.f;
        #pragma unroll
        for (int b = 0; b < MB; ++b) s += ysum[b];
        atomicAdd(&ws[WS_ACC+1], s);
    }
}

// ================= finalize scalars =================
__global__ void rits_fin(const float* __restrict__ ws, float* __restrict__ out)
{
    if (blockIdx.x == 0 && threadIdx.x == 0) {
        float xl = ws[WS_ACC] * 0.3f;
        float yl = ws[WS_ACC+1] * (1.0f / (8192.0f + 1e-5f));
        out[0] = xl; out[1] = yl; out[2] = xl + yl;
    }
}

extern "C" void kernel_launch(void* const* d_in, const int* in_sizes, int n_in,
                              void* d_out, int out_size, void* d_ws, size_t ws_size,
                              hipStream_t stream)
{
    const float* values = (const float*)d_in[0];
    const float* masks  = (const float*)d_in[1];
    const float* deltas = (const float*)d_in[2];
    const float* probs  = (const float*)d_in[3];
    const float* ancil  = (const float*)d_in[4];
    const int*   labels = (const int*)  d_in[5];
    const float* W_td_h = (const float*)d_in[6];
    const float* b_td_h = (const float*)d_in[7];
    const float* W_td_x = (const float*)d_in[8];
    const float* b_td_x = (const float*)d_in[9];
    const float* W_hist = (const float*)d_in[10];
    const float* b_hist = (const float*)d_in[11];
    const float* W_feat = (const float*)d_in[12];
    const float* b_feat = (const float*)d_in[13];
    const float* W_comb = (const float*)d_in[14];
    const float* b_comb = (const float*)d_in[15];
    const float* W_ih   = (const float*)d_in[16];
    const float* W_hh   = (const float*)d_in[17];
    const float* b_ih   = (const float*)d_in[18];
    const float* b_hh   = (const float*)d_in[19];
    const float* W_anc  = (const float*)d_in[20];
    const float* b_anc  = (const float*)d_in[21];
    const float* W_cat  = (const float*)d_in[22];
    const float* b_cat  = (const float*)d_in[23];
    const float* W_out  = (const float*)d_in[24];
    const float* b_out  = (const float*)d_in[25];
    float* ws  = (float*)d_ws;
    float* out = (float*)d_out;

    hipLaunchKernelGGL(rits_prep, dim3((H_*178 + 255)/256), dim3(256), 0, stream, W_cat, ws);
    hipLaunchKernelGGL(rits_msum, dim3(7*MS_BG), dim3(256), 0, stream, masks, ws);
    hipLaunchKernelGGL(rits_main, dim3(B_/NB), dim3(NTHR), 0, stream,
                       values, masks, deltas, W_td_h, b_td_h, W_td_x, b_td_x,
                       W_hist, b_hist, W_feat, b_feat, W_comb, b_comb,
                       W_ih, W_hh, b_ih, b_hh, ws, out);
    hipLaunchKernelGGL(rits_head, dim3(B_/MB), dim3(128), 0, stream,
                       probs, ancil, labels, W_anc, b_anc, b_cat, W_out, b_out, ws, out);
    hipLaunchKernelGGL(rits_fin, dim3(1), dim3(1), 0, stream, ws, out);
}